// Round 2
// baseline (129.239 us; speedup 1.0000x reference)
//
#include <hip/hip_runtime.h>

// CBOWSubword: out[t,:] = W[seq[t],:] + W[pre[t],:] + W[post[t],:]
// B*S = 131072 tokens, D = 128 fp32 (= 32 float4 per row).
//
// R2: 4 tokens per thread. All 12 index loads issued first, then all 12
// row-gathers (12 KB outstanding per wave vs 3 KB in R1) — amortizes the
// idx->gather serial dependency that capped MLP. Output uses nontemporal
// stores so the 64 MiB stream doesn't evict the 51 MB table from L2.

#define D4 32   // 128 floats / 4 per float4
#define TPT 4   // tokens per thread

typedef float v4f __attribute__((ext_vector_type(4)));

__global__ __launch_bounds__(256) void cbow_gather3_x4_kernel(
    const int* __restrict__ seq,
    const int* __restrict__ pre,
    const int* __restrict__ post,
    const v4f* __restrict__ weight,
    v4f* __restrict__ out,
    int n_tokens, int chunk)
{
    int tid  = blockIdx.x * blockDim.x + threadIdx.x;
    int lane = tid & 31;       // which float4 of the 128-float row
    int slot = tid >> 5;       // token index within the first chunk
    if (slot >= chunk) return;

    int  tok[TPT];
    bool val[TPT];
#pragma unroll
    for (int k = 0; k < TPT; ++k) {
        tok[k] = slot + k * chunk;
        val[k] = tok[k] < n_tokens;
    }

    // Phase 1: all index loads in flight together.
    int is[TPT], ip[TPT], iq[TPT];
#pragma unroll
    for (int k = 0; k < TPT; ++k) {
        if (val[k]) {
            is[k] = seq[tok[k]];
            ip[k] = pre[tok[k]];
            iq[k] = post[tok[k]];
        } else {
            is[k] = ip[k] = iq[k] = 0;
        }
    }

    // Phase 2: all 12 row-gathers in flight together (12 KB/wave outstanding).
    v4f a[TPT], b[TPT], c[TPT];
#pragma unroll
    for (int k = 0; k < TPT; ++k) {
        a[k] = weight[(size_t)is[k] * D4 + lane];
        b[k] = weight[(size_t)ip[k] * D4 + lane];
        c[k] = weight[(size_t)iq[k] * D4 + lane];
    }

    // Phase 3: sum + nontemporal store (don't pollute L2 with the stream).
#pragma unroll
    for (int k = 0; k < TPT; ++k) {
        if (val[k]) {
            v4f r = a[k] + b[k] + c[k];
            __builtin_nontemporal_store(r, &out[(size_t)tok[k] * D4 + lane]);
        }
    }
}

extern "C" void kernel_launch(void* const* d_in, const int* in_sizes, int n_in,
                              void* d_out, int out_size, void* d_ws, size_t ws_size,
                              hipStream_t stream)
{
    const int* seq    = (const int*)d_in[0];
    const int* pre    = (const int*)d_in[1];
    const int* post   = (const int*)d_in[2];
    const v4f* weight = (const v4f*)d_in[3];
    v4f*       out    = (v4f*)d_out;

    const int n_tokens = in_sizes[0];               // 128*1024 = 131072
    const int chunk = (n_tokens + TPT - 1) / TPT;   // tokens per k-slice
    const long total_threads = (long)chunk * 32;
    const int block = 256;
    const int grid = (int)((total_threads + block - 1) / block);

    cbow_gather3_x4_kernel<<<grid, block, 0, stream>>>(
        seq, pre, post, weight, out, n_tokens, chunk);
}